// Round 10
// baseline (650.627 us; speedup 1.0000x reference)
//
#include <hip/hip_runtime.h>

#define NN 50000
#define NE 500000
#define HD 128
#define HD2 256
#define NL 4
#define NG 1000

constexpr float MSG_EPS = 1e-7f;
constexpr float LNEPS   = 1e-5f;

typedef float  f32x4  __attribute__((ext_vector_type(4)));
typedef __bf16 bf16x8 __attribute__((ext_vector_type(8)));

__device__ __forceinline__ unsigned short f2b(float f) {
    unsigned int u = __float_as_uint(f);
    unsigned int r = u + 0x7FFFu + ((u >> 16) & 1u);
    return (unsigned short)(r >> 16);
}
__device__ __forceinline__ float b2f(unsigned short h) {
    return __uint_as_float(((unsigned int)h) << 16);
}
__device__ __forceinline__ unsigned int pack2(float a, float b) {
    return (unsigned int)f2b(a) | ((unsigned int)f2b(b) << 16);
}

// ---------------- merged setup: weight prep + node encoder + dst histogram ----------
#define PREP_BLKS 512
#define ENC_BLKS 25000  // 2 nodes per 256-thr block
#define HIST_BLKS ((NE + 255) / 256)

__global__ void k_setup(const float* __restrict__ x, const float* __restrict__ encW,
                        const float* __restrict__ encB, unsigned short* __restrict__ zb,
                        const float* __restrict__ W1, const float* __restrict__ W2,
                        unsigned short* __restrict__ W1T, unsigned short* __restrict__ W2T,
                        const int* __restrict__ dst, int* __restrict__ counts) {
    int bid = blockIdx.x, tid = threadIdx.x;
    if (bid < PREP_BLKS) {
        int idx = bid * 256 + tid;  // 131072 total
        {
            int k = idx & 127, n = (idx >> 7) & 255, l = idx >> 15;
            W1T[idx] = f2b(W1[(l * 128 + k) * 256 + n]);
        }
        {
            int k = idx & 255, n = (idx >> 8) & 127, l = idx >> 15;
            W2T[idx] = f2b(W2[(l * 256 + k) * 128 + n]);
        }
    } else if (bid < PREP_BLKS + ENC_BLKS) {
        int n = (bid - PREP_BLKS) * 2 + (tid >> 7);
        int c = tid & 127;
        float xr[9];
#pragma unroll
        for (int k = 0; k < 9; k++) xr[k] = x[n * 9 + k];
        float acc = encB[c];
#pragma unroll
        for (int k = 0; k < 9; k++) acc = fmaf(xr[k], encW[k * HD + c], acc);
        zb[(size_t)n * HD + c] = f2b(acc);
    } else {
        int e = (bid - PREP_BLKS - ENC_BLKS) * 256 + tid;
        if (e < NE) atomicAdd(&counts[dst[e]], 1);
    }
}

// ---------------- CSR scan ----------------
#define SCAN_B 512
#define NSB ((NN + SCAN_B - 1) / SCAN_B)  // 98

__global__ void k_scan1(const int* __restrict__ counts, int* __restrict__ incl,
                        int* __restrict__ bsum) {
    __shared__ int s[SCAN_B];
    int i = blockIdx.x * SCAN_B + threadIdx.x;
    int v = (i < NN) ? counts[i] : 0;
    s[threadIdx.x] = v;
    __syncthreads();
    for (int off = 1; off < SCAN_B; off <<= 1) {
        int t = (threadIdx.x >= off) ? s[threadIdx.x - off] : 0;
        __syncthreads();
        s[threadIdx.x] += t;
        __syncthreads();
    }
    if (i < NN) incl[i] = s[threadIdx.x];
    if (threadIdx.x == SCAN_B - 1) bsum[blockIdx.x] = s[threadIdx.x];
}

__global__ void k_scan2(const int* __restrict__ bsum, int* __restrict__ boff, int nb) {
    __shared__ int s[128];
    int v = (threadIdx.x < nb) ? bsum[threadIdx.x] : 0;
    s[threadIdx.x] = v;
    __syncthreads();
    for (int off = 1; off < 128; off <<= 1) {
        int t = (threadIdx.x >= off) ? s[threadIdx.x - off] : 0;
        __syncthreads();
        s[threadIdx.x] += t;
        __syncthreads();
    }
    if (threadIdx.x < nb) boff[threadIdx.x] = s[threadIdx.x] - v;  // exclusive
}

// scan finalize + group-bounds binary search (merged)
__global__ void k_scan3g(const int* __restrict__ incl, const int* __restrict__ boff,
                         int* __restrict__ row_start, const int* __restrict__ batch,
                         int* __restrict__ gstart) {
    if (blockIdx.x < NSB) {
        int i = blockIdx.x * SCAN_B + threadIdx.x;
        if (i < NN) row_start[i + 1] = incl[i] + boff[blockIdx.x];
        if (i == 0) row_start[0] = 0;
    } else {
        int g = (blockIdx.x - NSB) * SCAN_B + threadIdx.x;
        if (g > NG) return;
        int lo = 0, hi = NN;
        while (lo < hi) {
            int mid = (lo + hi) >> 1;
            if (batch[mid] < g) lo = mid + 1;
            else hi = mid;
        }
        gstart[g] = lo;
    }
}

// pack {attr0, attr1, attr2, src} per CSR slot
__global__ void k_scatter(const int* __restrict__ src, const int* __restrict__ dst,
                          const float* __restrict__ eattr, const int* __restrict__ row_start,
                          int* __restrict__ cursor, float4* __restrict__ aperm) {
    int e = blockIdx.x * blockDim.x + threadIdx.x;
    if (e >= NE) return;
    int d = dst[e];
    int p = row_start[d] + atomicAdd(&cursor[d], 1);
    float4 v;
    v.x = eattr[e * 3 + 0];
    v.y = eattr[e * 3 + 1];
    v.z = eattr[e * 3 + 2];
    v.w = __int_as_float(src[e]);
    aperm[p] = v;
}

// ---------------- per-edge softmax-agg accumulate (2 channels/lane) ----------------
__device__ __forceinline__ void edge_acc2(float4 a, unsigned int zz, float2 w0, float2 w1,
                                          float2 w2, float2 bb, float tv, float& num0,
                                          float& num1, float& wm0, float& wm1) {
    float zx = b2f((unsigned short)zz), zy = b2f((unsigned short)(zz >> 16));
    float eax = fmaf(a.x, w0.x, fmaf(a.y, w1.x, fmaf(a.z, w2.x, bb.x)));
    float eay = fmaf(a.x, w0.y, fmaf(a.y, w1.y, fmaf(a.z, w2.y, bb.y)));
    float mx = fmaxf(zx + eax, 0.f) + MSG_EPS;
    float my = fmaxf(zy + eay, 0.f) + MSG_EPS;
    float ex = __expf(tv * mx), ey = __expf(tv * my);
    num0 += ex;
    num1 += ey;
    wm0 = fmaf(mx, ex, wm0);
    wm1 = fmaf(my, ey, wm1);
}

// ---------------- softmax aggregation: one wave per node, 2 ch/lane, unroll-8 ------
// Gather base scalarized via readfirstlane (sj is wave-uniform -> SALU addr + saddr load).
__global__ __launch_bounds__(256) void k_aggregate(const unsigned short* __restrict__ zbin,
                                                   const float4* __restrict__ aperm,
                                                   const int* __restrict__ row_start,
                                                   const float* __restrict__ We,
                                                   const float* __restrict__ be,
                                                   const float* __restrict__ t, int layer,
                                                   unsigned int* __restrict__ outb) {
    int w = threadIdx.x >> 6, lane = threadIdx.x & 63;
    int n = blockIdx.x * 4 + w;
    if (n >= NN) return;
    int c = lane * 2;
    float2 w0 = *(const float2*)&We[c];
    float2 w1 = *(const float2*)&We[HD + c];
    float2 w2 = *(const float2*)&We[2 * HD + c];
    float2 bb = *(const float2*)&be[c];
    float tv = t[layer];
    int s0 = row_start[n], s1 = row_start[n + 1];
    float num0 = 0.f, num1 = 0.f, wm0 = 0.f, wm1 = 0.f;
    const unsigned int* z32 = (const unsigned int*)zbin;
    int p = s0;
    for (; p + 8 <= s1; p += 8) {
        float4 A[8];
#pragma unroll
        for (int j = 0; j < 8; j++) A[j] = aperm[p + j];
        unsigned int Z[8];
#pragma unroll
        for (int j = 0; j < 8; j++) {
            int sj = __builtin_amdgcn_readfirstlane(__float_as_int(A[j].w));
            Z[j] = z32[(size_t)sj * 64 + lane];
        }
#pragma unroll
        for (int j = 0; j < 8; j++)
            edge_acc2(A[j], Z[j], w0, w1, w2, bb, tv, num0, num1, wm0, wm1);
    }
    for (; p + 4 <= s1; p += 4) {
        float4 A[4];
#pragma unroll
        for (int j = 0; j < 4; j++) A[j] = aperm[p + j];
        unsigned int Z[4];
#pragma unroll
        for (int j = 0; j < 4; j++) {
            int sj = __builtin_amdgcn_readfirstlane(__float_as_int(A[j].w));
            Z[j] = z32[(size_t)sj * 64 + lane];
        }
#pragma unroll
        for (int j = 0; j < 4; j++)
            edge_acc2(A[j], Z[j], w0, w1, w2, bb, tv, num0, num1, wm0, wm1);
    }
    for (; p < s1; p++) {
        float4 a = aperm[p];
        int sj = __builtin_amdgcn_readfirstlane(__float_as_int(a.w));
        unsigned int zz = z32[(size_t)sj * 64 + lane];
        edge_acc2(a, zz, w0, w1, w2, bb, tv, num0, num1, wm0, wm1);
    }
    unsigned int zn = z32[(size_t)n * 64 + lane];
    float ox = ((s1 > s0) ? (wm0 / num0) : 0.f) + b2f((unsigned short)zn);
    float oy = ((s1 > s0) ? (wm1 / num1) : 0.f) + b2f((unsigned short)(zn >> 16));
    outb[(size_t)n * 64 + lane] = pack2(ox, oy);
}

// ---------------- wave-private MFMA MLP + next-layer LN, ZERO barriers --------------
// Block = 4 independent waves; each wave owns 16 rows end-to-end:
// GEMM1 (full 256 cols) -> in-register LN(256) -> private Hs (LDS transpose) ->
// GEMM2 (full 128 cols) -> private Ht -> coalesced row-wise epilogue (h, LN(128), zb).
// 50000 = 782*64 with exact 16-row waves; inactive waves return early (no barriers).
#define HS_LD 268  // bf16 row stride
#define HT_LD 136  // bf16 row stride; as uint: 68

__global__ __launch_bounds__(256) void k_mlp(const unsigned short* __restrict__ outb,
                                             const unsigned short* __restrict__ W1T,
                                             const float* __restrict__ b1l,
                                             const float* __restrict__ lgl,
                                             const float* __restrict__ lbl,
                                             const unsigned short* __restrict__ W2T,
                                             const float* __restrict__ b2l,
                                             unsigned short* __restrict__ h,
                                             const float* __restrict__ gn,
                                             const float* __restrict__ bn,
                                             unsigned short* __restrict__ zb,
                                             int add_residual) {
    __shared__ __align__(16) unsigned short Hs[4 * 16 * HS_LD];  // 34304 B
    __shared__ __align__(16) unsigned short Ht[4 * 16 * HT_LD];  // 17408 B

    int tid = threadIdx.x;
    int w = tid >> 6, lane = tid & 63, q = lane >> 4, i = lane & 15;
    int base = blockIdx.x * 64 + w * 16;
    if (base >= NN) return;  // whole-wave exit; kernel has no barriers
    unsigned short* hs = Hs + w * 16 * HS_LD;
    unsigned short* ht = Ht + w * 16 * HT_LD;

    // ---- GEMM1: 16 rows x 256 cols, K=128; A direct from global bf16 ----
    f32x4 acc[16];
#pragma unroll
    for (int ct = 0; ct < 16; ct++) acc[ct] = (f32x4){0.f, 0.f, 0.f, 0.f};
#pragma unroll
    for (int ks = 0; ks < 4; ks++) {
        bf16x8 a = *(const bf16x8*)&outb[(size_t)(base + i) * HD + ks * 32 + q * 8];
#pragma unroll
        for (int ct = 0; ct < 16; ct++) {
            bf16x8 bfr = *(const bf16x8*)&W1T[(ct * 16 + i) * HD + ks * 32 + q * 8];
            acc[ct] = __builtin_amdgcn_mfma_f32_16x16x32_bf16(a, bfr, acc[ct], 0, 0, 0);
        }
    }
#pragma unroll
    for (int ct = 0; ct < 16; ct++) {
        float bb = b1l[ct * 16 + i];
#pragma unroll
        for (int r = 0; r < 4; r++) acc[ct][r] += bb;
    }

    // ---- LN(256)+relu in-register; lane holds rows q*4+r, cols ct*16+i ----
    {
        float s[4] = {0.f, 0.f, 0.f, 0.f}, sq[4] = {0.f, 0.f, 0.f, 0.f};
#pragma unroll
        for (int ct = 0; ct < 16; ct++)
#pragma unroll
            for (int r = 0; r < 4; r++) {
                s[r] += acc[ct][r];
                sq[r] = fmaf(acc[ct][r], acc[ct][r], sq[r]);
            }
#pragma unroll
        for (int m = 8; m >= 1; m >>= 1)
#pragma unroll
            for (int r = 0; r < 4; r++) {
                s[r] += __shfl_xor(s[r], m);
                sq[r] += __shfl_xor(sq[r], m);
            }
        float mu[4], inv[4];
#pragma unroll
        for (int r = 0; r < 4; r++) {
            mu[r] = s[r] * (1.f / 256.f);
            float var = sq[r] * (1.f / 256.f) - mu[r] * mu[r];
            inv[r] = rsqrtf(var + LNEPS);
        }
#pragma unroll
        for (int ct = 0; ct < 16; ct++) {
            float g = lgl[ct * 16 + i];
            float cb = lbl[ct * 16 + i];
#pragma unroll
            for (int r = 0; r < 4; r++) {
                float v = fmaxf(fmaf((acc[ct][r] - mu[r]) * inv[r], g, cb), 0.f);
                hs[(q * 4 + r) * HS_LD + ct * 16 + i] = f2b(v);
            }
        }
    }
    // same-wave ds_write -> ds_read: compiler inserts lgkmcnt wait; no barrier needed

    // ---- GEMM2: 16 rows x 128 cols, K=256 ----
    f32x4 acc2[8];
#pragma unroll
    for (int ct = 0; ct < 8; ct++) acc2[ct] = (f32x4){0.f, 0.f, 0.f, 0.f};
#pragma unroll
    for (int ks = 0; ks < 8; ks++) {
        bf16x8 a = *(const bf16x8*)&hs[i * HS_LD + ks * 32 + q * 8];
#pragma unroll
        for (int ct = 0; ct < 8; ct++) {
            bf16x8 bfr = *(const bf16x8*)&W2T[(ct * 16 + i) * HD2 + ks * 32 + q * 8];
            acc2[ct] = __builtin_amdgcn_mfma_f32_16x16x32_bf16(a, bfr, acc2[ct], 0, 0, 0);
        }
    }

    // ---- conv-out (+b2) -> private bf16 Ht tile (C-layout scatter; LDS absorbs) ----
#pragma unroll
    for (int ct = 0; ct < 8; ct++) {
        float bb = b2l[ct * 16 + i];
#pragma unroll
        for (int r = 0; r < 4; r++)
            ht[(q * 4 + r) * HT_LD + ct * 16 + i] = f2b(acc2[ct][r] + bb);
    }

    // ---- row-wise COALESCED epilogue: residual add, h store, LN(128), zb store ----
    {
        const unsigned int* ht32 = (const unsigned int*)ht;
        unsigned int* h32 = (unsigned int*)h;
        unsigned int* zb32 = (unsigned int*)zb;
        float2 gg = *(const float2*)&gn[lane * 2];
        float2 cc = *(const float2*)&bn[lane * 2];
        for (int rr = 0; rr < 16; rr++) {
            int row = base + rr;
            unsigned int tv = ht32[rr * (HT_LD / 2) + lane];
            float cx = b2f((unsigned short)tv), cy = b2f((unsigned short)(tv >> 16));
            if (add_residual) {
                unsigned int hv = h32[(size_t)row * 64 + lane];
                cx += b2f((unsigned short)hv);
                cy += b2f((unsigned short)(hv >> 16));
            }
            h32[(size_t)row * 64 + lane] = pack2(cx, cy);
            float s = cx + cy, sq = cx * cx + cy * cy;
#pragma unroll
            for (int m = 32; m >= 1; m >>= 1) {
                s += __shfl_xor(s, m);
                sq += __shfl_xor(sq, m);
            }
            float mu = s * (1.f / 128.f);
            float var = sq * (1.f / 128.f) - mu * mu;
            float inv = rsqrtf(var + LNEPS);
            float z0 = fmaxf(fmaf((cx - mu) * inv, gg.x, cc.x), 0.f);
            float z1 = fmaxf(fmaf((cy - mu) * inv, gg.y, cc.y), 0.f);
            zb32[(size_t)row * 64 + lane] = pack2(z0, z1);
        }
    }
}

// ---------------- atomic-free global mean pool (batch is sorted) ----------------
__global__ void k_pool(const unsigned short* __restrict__ zb, const int* __restrict__ gstart,
                       float* __restrict__ out) {
    int g = blockIdx.x;
    int c = threadIdx.x;  // 128
    int a = gstart[g], b = gstart[g + 1];
    float s0 = 0.f, s1 = 0.f;
    int n = a;
    for (; n + 2 <= b; n += 2) {
        s0 += b2f(zb[(size_t)n * HD + c]);
        s1 += b2f(zb[(size_t)(n + 1) * HD + c]);
    }
    if (n < b) s0 += b2f(zb[(size_t)n * HD + c]);
    out[g * HD + c] = (s0 + s1) / fmaxf((float)(b - a), 1.f);
}

// ---------------- launch ----------------
extern "C" void kernel_launch(void* const* d_in, const int* in_sizes, int n_in, void* d_out,
                              int out_size, void* d_ws, size_t ws_size, hipStream_t stream) {
    const float* x     = (const float*)d_in[0];
    const int* ei      = (const int*)d_in[1];
    const float* eattr = (const float*)d_in[2];
    const int* batch   = (const int*)d_in[3];
    const float* encW  = (const float*)d_in[4];
    const float* encB  = (const float*)d_in[5];
    const float* eW    = (const float*)d_in[6];
    const float* eB    = (const float*)d_in[7];
    const float* ln_g  = (const float*)d_in[8];
    const float* ln_b  = (const float*)d_in[9];
    const float* W1    = (const float*)d_in[10];
    const float* b1    = (const float*)d_in[11];
    const float* mlg   = (const float*)d_in[12];
    const float* mlb   = (const float*)d_in[13];
    const float* W2    = (const float*)d_in[14];
    const float* b2    = (const float*)d_in[15];
    const float* t     = (const float*)d_in[16];
    const int* src = ei;
    const int* dst = ei + NE;

    char* w = (char*)d_ws;
    auto alloc = [&](size_t bytes) {
        char* p = w;
        w += (bytes + 255) & ~size_t(255);
        return p;
    };
    unsigned short* h    = (unsigned short*)alloc(sizeof(unsigned short) * NN * HD);
    unsigned short* zb   = (unsigned short*)alloc(sizeof(unsigned short) * NN * HD);
    unsigned int* outb   = (unsigned int*)alloc(sizeof(unsigned int) * NN * HD / 2);
    float4* aperm        = (float4*)alloc(sizeof(float4) * NE);
    int* row_start       = (int*)alloc(sizeof(int) * (NN + 1));
    int* counts          = (int*)alloc(sizeof(int) * NN);
    int* cursor          = (int*)alloc(sizeof(int) * NN);
    int* incl            = (int*)alloc(sizeof(int) * NN);
    int* bsum            = (int*)alloc(sizeof(int) * 128);
    int* boff            = (int*)alloc(sizeof(int) * 128);
    int* gstart          = (int*)alloc(sizeof(int) * (NG + 1));
    unsigned short* W1T  = (unsigned short*)alloc(sizeof(unsigned short) * NL * HD * HD2);
    unsigned short* W2T  = (unsigned short*)alloc(sizeof(unsigned short) * NL * HD2 * HD);

    hipMemsetAsync(counts, 0, sizeof(int) * NN, stream);
    hipMemsetAsync(cursor, 0, sizeof(int) * NN, stream);

    k_setup<<<PREP_BLKS + ENC_BLKS + HIST_BLKS, 256, 0, stream>>>(x, encW, encB, zb, W1, W2,
                                                                  W1T, W2T, dst, counts);
    k_scan1<<<NSB, SCAN_B, 0, stream>>>(counts, incl, bsum);
    k_scan2<<<1, 128, 0, stream>>>(bsum, boff, NSB);
    k_scan3g<<<NSB + 2, SCAN_B, 0, stream>>>(incl, boff, row_start, batch, gstart);
    k_scatter<<<(NE + 255) / 256, 256, 0, stream>>>(src, dst, eattr, row_start, cursor, aperm);

    for (int l = 0; l < NL; l++) {
        k_aggregate<<<(NN + 3) / 4, 256, 0, stream>>>(zb, aperm, row_start, eW, eB, t, l, outb);
        int ln_next = (l + 1) % NL;  // layer 3 fuses the final ln (reuses layer-0 params)
        k_mlp<<<(NN + 63) / 64, 256, 0, stream>>>(
            (const unsigned short*)outb, W1T + (size_t)l * HD * HD2, b1 + l * HD2,
            mlg + l * HD2, mlb + l * HD2, W2T + (size_t)l * HD2 * HD, b2 + l * HD, h,
            ln_g + ln_next * HD, ln_b + ln_next * HD, zb, l > 0);
    }
    k_pool<<<NG, HD, 0, stream>>>(zb, gstart, (float*)d_out);
}

// Round 11
// 546.962 us; speedup vs baseline: 1.1895x; 1.1895x over previous
//
#include <hip/hip_runtime.h>

#define NN 50000
#define NE 500000
#define HD 128
#define HD2 256
#define NL 4
#define NG 1000

constexpr float MSG_EPS = 1e-7f;
constexpr float LNEPS   = 1e-5f;

typedef float  f32x4  __attribute__((ext_vector_type(4)));
typedef __bf16 bf16x8 __attribute__((ext_vector_type(8)));

__device__ __forceinline__ unsigned short f2b(float f) {
    unsigned int u = __float_as_uint(f);
    unsigned int r = u + 0x7FFFu + ((u >> 16) & 1u);
    return (unsigned short)(r >> 16);
}
__device__ __forceinline__ float b2f(unsigned short h) {
    return __uint_as_float(((unsigned int)h) << 16);
}
__device__ __forceinline__ unsigned int pack2(float a, float b) {
    return (unsigned int)f2b(a) | ((unsigned int)f2b(b) << 16);
}

// ---------------- merged setup: weight prep + node encoder + dst histogram ----------
#define PREP_BLKS 512
#define ENC_BLKS 25000  // 2 nodes per 256-thr block
#define HIST_BLKS ((NE + 255) / 256)

__global__ void k_setup(const float* __restrict__ x, const float* __restrict__ encW,
                        const float* __restrict__ encB, unsigned short* __restrict__ zb,
                        const float* __restrict__ W1, const float* __restrict__ W2,
                        unsigned short* __restrict__ W1T, unsigned short* __restrict__ W2T,
                        const int* __restrict__ dst, int* __restrict__ counts) {
    int bid = blockIdx.x, tid = threadIdx.x;
    if (bid < PREP_BLKS) {
        int idx = bid * 256 + tid;  // 131072 total
        {
            int k = idx & 127, n = (idx >> 7) & 255, l = idx >> 15;
            W1T[idx] = f2b(W1[(l * 128 + k) * 256 + n]);
        }
        {
            int k = idx & 255, n = (idx >> 8) & 127, l = idx >> 15;
            W2T[idx] = f2b(W2[(l * 256 + k) * 128 + n]);
        }
    } else if (bid < PREP_BLKS + ENC_BLKS) {
        int n = (bid - PREP_BLKS) * 2 + (tid >> 7);
        int c = tid & 127;
        float xr[9];
#pragma unroll
        for (int k = 0; k < 9; k++) xr[k] = x[n * 9 + k];
        float acc = encB[c];
#pragma unroll
        for (int k = 0; k < 9; k++) acc = fmaf(xr[k], encW[k * HD + c], acc);
        zb[(size_t)n * HD + c] = f2b(acc);
    } else {
        int e = (bid - PREP_BLKS - ENC_BLKS) * 256 + tid;
        if (e < NE) atomicAdd(&counts[dst[e]], 1);
    }
}

// ---------------- CSR scan ----------------
#define SCAN_B 512
#define NSB ((NN + SCAN_B - 1) / SCAN_B)  // 98

__global__ void k_scan1(const int* __restrict__ counts, int* __restrict__ incl,
                        int* __restrict__ bsum) {
    __shared__ int s[SCAN_B];
    int i = blockIdx.x * SCAN_B + threadIdx.x;
    int v = (i < NN) ? counts[i] : 0;
    s[threadIdx.x] = v;
    __syncthreads();
    for (int off = 1; off < SCAN_B; off <<= 1) {
        int t = (threadIdx.x >= off) ? s[threadIdx.x - off] : 0;
        __syncthreads();
        s[threadIdx.x] += t;
        __syncthreads();
    }
    if (i < NN) incl[i] = s[threadIdx.x];
    if (threadIdx.x == SCAN_B - 1) bsum[blockIdx.x] = s[threadIdx.x];
}

__global__ void k_scan2(const int* __restrict__ bsum, int* __restrict__ boff, int nb) {
    __shared__ int s[128];
    int v = (threadIdx.x < nb) ? bsum[threadIdx.x] : 0;
    s[threadIdx.x] = v;
    __syncthreads();
    for (int off = 1; off < 128; off <<= 1) {
        int t = (threadIdx.x >= off) ? s[threadIdx.x - off] : 0;
        __syncthreads();
        s[threadIdx.x] += t;
        __syncthreads();
    }
    if (threadIdx.x < nb) boff[threadIdx.x] = s[threadIdx.x] - v;  // exclusive
}

// scan finalize + group-bounds binary search (merged)
__global__ void k_scan3g(const int* __restrict__ incl, const int* __restrict__ boff,
                         int* __restrict__ row_start, const int* __restrict__ batch,
                         int* __restrict__ gstart) {
    if (blockIdx.x < NSB) {
        int i = blockIdx.x * SCAN_B + threadIdx.x;
        if (i < NN) row_start[i + 1] = incl[i] + boff[blockIdx.x];
        if (i == 0) row_start[0] = 0;
    } else {
        int g = (blockIdx.x - NSB) * SCAN_B + threadIdx.x;
        if (g > NG) return;
        int lo = 0, hi = NN;
        while (lo < hi) {
            int mid = (lo + hi) >> 1;
            if (batch[mid] < g) lo = mid + 1;
            else hi = mid;
        }
        gstart[g] = lo;
    }
}

// pack {attr0, attr1, attr2, src} per CSR slot
__global__ void k_scatter(const int* __restrict__ src, const int* __restrict__ dst,
                          const float* __restrict__ eattr, const int* __restrict__ row_start,
                          int* __restrict__ cursor, float4* __restrict__ aperm) {
    int e = blockIdx.x * blockDim.x + threadIdx.x;
    if (e >= NE) return;
    int d = dst[e];
    int p = row_start[d] + atomicAdd(&cursor[d], 1);
    float4 v;
    v.x = eattr[e * 3 + 0];
    v.y = eattr[e * 3 + 1];
    v.z = eattr[e * 3 + 2];
    v.w = __int_as_float(src[e]);
    aperm[p] = v;
}

// ---------------- per-edge softmax-agg accumulate (2 channels/lane) ----------------
__device__ __forceinline__ void edge_acc2(float4 a, unsigned int zz, float2 w0, float2 w1,
                                          float2 w2, float2 bb, float tv, float& num0,
                                          float& num1, float& wm0, float& wm1) {
    float zx = b2f((unsigned short)zz), zy = b2f((unsigned short)(zz >> 16));
    float eax = fmaf(a.x, w0.x, fmaf(a.y, w1.x, fmaf(a.z, w2.x, bb.x)));
    float eay = fmaf(a.x, w0.y, fmaf(a.y, w1.y, fmaf(a.z, w2.y, bb.y)));
    float mx = fmaxf(zx + eax, 0.f) + MSG_EPS;
    float my = fmaxf(zy + eay, 0.f) + MSG_EPS;
    float ex = __expf(tv * mx), ey = __expf(tv * my);
    num0 += ex;
    num1 += ey;
    wm0 = fmaf(mx, ex, wm0);
    wm1 = fmaf(my, ey, wm1);
}

// ---------------- softmax aggregation: EDGE-SPLIT, 2 waves per node ----------------
// Block = 256 thr = 4 waves = 2 nodes x 2 edge-halves. Each edge processed ONCE
// (2 ch/lane, full 128 ch per wave); partial (num,wm) summed via 4KB LDS + 1 barrier.
// Doubles TLP (100K waves) at identical total per-edge VALU work.
__global__ __launch_bounds__(256) void k_aggregate(const unsigned short* __restrict__ zbin,
                                                   const float4* __restrict__ aperm,
                                                   const int* __restrict__ row_start,
                                                   const float* __restrict__ We,
                                                   const float* __restrict__ be,
                                                   const float* __restrict__ t, int layer,
                                                   unsigned int* __restrict__ outb) {
    __shared__ float4 part[4][64];
    int w = threadIdx.x >> 6, lane = threadIdx.x & 63;
    int n = blockIdx.x * 2 + (w >> 1);  // grid = NN/2 exact
    int half = w & 1;
    int c = lane * 2;
    float2 w0 = *(const float2*)&We[c];
    float2 w1 = *(const float2*)&We[HD + c];
    float2 w2 = *(const float2*)&We[2 * HD + c];
    float2 bb = *(const float2*)&be[c];
    float tv = t[layer];
    int s0 = row_start[n], s1 = row_start[n + 1];
    int mid = s0 + ((s1 - s0 + 1) >> 1);
    int lo = half ? mid : s0;
    int hi = half ? s1 : mid;
    float num0 = 0.f, num1 = 0.f, wm0 = 0.f, wm1 = 0.f;
    const unsigned int* z32 = (const unsigned int*)zbin;
    int p = lo;
    for (; p + 4 <= hi; p += 4) {
        float4 A[4];
#pragma unroll
        for (int j = 0; j < 4; j++) A[j] = aperm[p + j];
        unsigned int Z[4];
#pragma unroll
        for (int j = 0; j < 4; j++) {
            int sj = __builtin_amdgcn_readfirstlane(__float_as_int(A[j].w));
            Z[j] = z32[(size_t)sj * 64 + lane];
        }
#pragma unroll
        for (int j = 0; j < 4; j++)
            edge_acc2(A[j], Z[j], w0, w1, w2, bb, tv, num0, num1, wm0, wm1);
    }
    for (; p < hi; p++) {
        float4 a = aperm[p];
        int sj = __builtin_amdgcn_readfirstlane(__float_as_int(a.w));
        unsigned int zz = z32[(size_t)sj * 64 + lane];
        edge_acc2(a, zz, w0, w1, w2, bb, tv, num0, num1, wm0, wm1);
    }
    part[w][lane] = make_float4(num0, num1, wm0, wm1);
    __syncthreads();
    if (half == 0) {
        float4 a = part[w][lane];
        float4 b = part[w + 1][lane];
        float n0 = a.x + b.x, n1 = a.y + b.y;
        float m0 = a.z + b.z, m1 = a.w + b.w;
        unsigned int zn = z32[(size_t)n * 64 + lane];
        bool has = s1 > s0;
        float ox = (has ? (m0 / n0) : 0.f) + b2f((unsigned short)zn);
        float oy = (has ? (m1 / n1) : 0.f) + b2f((unsigned short)(zn >> 16));
        outb[(size_t)n * 64 + lane] = pack2(ox, oy);
    }
}

// ---------------- fused MFMA MLP + next-layer LN+relu (R9 version) ----------------
// hnew = (add? h : 0) + relu(LN(A@W1+b1))@W2+b2 ; h=bf16(hnew); zb=bf16(relu(LN_next(hnew)))
// BM=32, 4 waves. In-register LN1 stats (st1 LDS exchange). Register lookahead GEMMs.
// GEMM2 out -> bf16 LDS tile Ht (C-layout scatter), then row-wise COALESCED epilogue.
#define BM 32
#define HS_LD 264  // bf16 row stride (256+8)
#define HT_LD 136  // bf16 row stride (128+8); as uint: 68

__global__ __launch_bounds__(256) void k_mlp(const unsigned short* __restrict__ outb,
                                             const unsigned short* __restrict__ W1T,
                                             const float* __restrict__ b1l,
                                             const float* __restrict__ lgl,
                                             const float* __restrict__ lbl,
                                             const unsigned short* __restrict__ W2T,
                                             const float* __restrict__ b2l,
                                             unsigned short* __restrict__ h,
                                             const float* __restrict__ gn,
                                             const float* __restrict__ bn,
                                             unsigned short* __restrict__ zb,
                                             int add_residual) {
    __shared__ __align__(16) unsigned short Hs[BM * HS_LD];  // 16896 B
    __shared__ __align__(16) unsigned short Ht[BM * HT_LD];  // 8704 B
    __shared__ __align__(16) float2 st1[2][16][4];           // 1024 B

    int nb = blockIdx.x * BM;
    int tid = threadIdx.x;
    int w = tid >> 6, lane = tid & 63, q = lane >> 4, i = lane & 15;

    // ---- GEMM1: 32x256, K=128; A from global bf16 outb, 1-step lookahead ----
    f32x4 acc[2][4];
#pragma unroll
    for (int rt = 0; rt < 2; rt++)
#pragma unroll
        for (int ct = 0; ct < 4; ct++) acc[rt][ct] = (f32x4){0.f, 0.f, 0.f, 0.f};

    bf16x8 acur[2], bcur[4];
#pragma unroll
    for (int rt = 0; rt < 2; rt++) {
        int row = nb + rt * 16 + i;
        acur[rt] = (row < NN) ? *(const bf16x8*)&outb[(size_t)row * HD + q * 8]
                              : (bf16x8)(__bf16)0.f;
    }
#pragma unroll
    for (int ct = 0; ct < 4; ct++)
        bcur[ct] = *(const bf16x8*)&W1T[(w * 64 + ct * 16 + i) * HD + q * 8];

#pragma unroll
    for (int ks = 0; ks < 4; ks++) {
        bf16x8 anxt[2], bnxt[4];
        if (ks < 3) {
#pragma unroll
            for (int rt = 0; rt < 2; rt++) {
                int row = nb + rt * 16 + i;
                anxt[rt] = (row < NN)
                               ? *(const bf16x8*)&outb[(size_t)row * HD + (ks + 1) * 32 + q * 8]
                               : (bf16x8)(__bf16)0.f;
            }
#pragma unroll
            for (int ct = 0; ct < 4; ct++)
                bnxt[ct] =
                    *(const bf16x8*)&W1T[(w * 64 + ct * 16 + i) * HD + (ks + 1) * 32 + q * 8];
        }
#pragma unroll
        for (int rt = 0; rt < 2; rt++)
#pragma unroll
            for (int ct = 0; ct < 4; ct++)
                acc[rt][ct] =
                    __builtin_amdgcn_mfma_f32_16x16x32_bf16(acur[rt], bcur[ct], acc[rt][ct],
                                                            0, 0, 0);
        if (ks < 3) {
#pragma unroll
            for (int rt = 0; rt < 2; rt++) acur[rt] = anxt[rt];
#pragma unroll
            for (int ct = 0; ct < 4; ct++) bcur[ct] = bnxt[ct];
        }
    }

    // ---- +b1 ----
#pragma unroll
    for (int ct = 0; ct < 4; ct++) {
        float bb = b1l[w * 64 + ct * 16 + i];
#pragma unroll
        for (int rt = 0; rt < 2; rt++)
#pragma unroll
            for (int r = 0; r < 4; r++) acc[rt][ct][r] += bb;
    }

    // ---- LN(256) stats in-register + cross-wave exchange ----
    {
        float sv[2][4], qv[2][4];
#pragma unroll
        for (int rt = 0; rt < 2; rt++)
#pragma unroll
            for (int r = 0; r < 4; r++) {
                float s = acc[rt][0][r] + acc[rt][1][r] + acc[rt][2][r] + acc[rt][3][r];
                float sq = 0.f;
#pragma unroll
                for (int ct = 0; ct < 4; ct++) sq = fmaf(acc[rt][ct][r], acc[rt][ct][r], sq);
                sv[rt][r] = s;
                qv[rt][r] = sq;
            }
#pragma unroll
        for (int m = 1; m <= 8; m <<= 1)
#pragma unroll
            for (int rt = 0; rt < 2; rt++)
#pragma unroll
                for (int r = 0; r < 4; r++) {
                    sv[rt][r] += __shfl_xor(sv[rt][r], m);
                    qv[rt][r] += __shfl_xor(qv[rt][r], m);
                }
        if (i == 0) {
#pragma unroll
            for (int rt = 0; rt < 2; rt++)
#pragma unroll
                for (int r = 0; r < 4; r++)
                    st1[rt][q * 4 + r][w] = make_float2(sv[rt][r], qv[rt][r]);
        }
    }
    __syncthreads();

    {
        float mu[2][4], inv[2][4];
#pragma unroll
        for (int rt = 0; rt < 2; rt++)
#pragma unroll
            for (int r = 0; r < 4; r++) {
                const float4* sp = (const float4*)&st1[rt][q * 4 + r][0];
                float4 a = sp[0], b = sp[1];
                float S = a.x + a.z + b.x + b.z;
                float Q = a.y + a.w + b.y + b.w;
                float m_ = S * (1.f / 256.f);
                float v_ = Q * (1.f / 256.f) - m_ * m_;
                mu[rt][r] = m_;
                inv[rt][r] = rsqrtf(v_ + LNEPS);
            }
#pragma unroll
        for (int ct = 0; ct < 4; ct++) {
            float g = lgl[w * 64 + ct * 16 + i];
            float c = lbl[w * 64 + ct * 16 + i];
#pragma unroll
            for (int rt = 0; rt < 2; rt++)
#pragma unroll
                for (int r = 0; r < 4; r++) {
                    float v =
                        fmaxf(fmaf((acc[rt][ct][r] - mu[rt][r]) * inv[rt][r], g, c), 0.f);
                    Hs[(rt * 16 + q * 4 + r) * HS_LD + w * 64 + ct * 16 + i] = f2b(v);
                }
        }
    }
    __syncthreads();

    // ---- GEMM2: 32x128, K=256; A from Hs, 1-step lookahead ----
    f32x4 acc2[2][2];
#pragma unroll
    for (int rt = 0; rt < 2; rt++)
#pragma unroll
        for (int ct = 0; ct < 2; ct++) acc2[rt][ct] = (f32x4){0.f, 0.f, 0.f, 0.f};

    bf16x8 hc[2], bc[2];
#pragma unroll
    for (int rt = 0; rt < 2; rt++) hc[rt] = *(const bf16x8*)&Hs[(rt * 16 + i) * HS_LD + q * 8];
#pragma unroll
    for (int ct = 0; ct < 2; ct++)
        bc[ct] = *(const bf16x8*)&W2T[(w * 32 + ct * 16 + i) * HD2 + q * 8];

#pragma unroll
    for (int ks = 0; ks < 8; ks++) {
        bf16x8 hn[2], bn2[2];
        if (ks < 7) {
#pragma unroll
            for (int rt = 0; rt < 2; rt++)
                hn[rt] = *(const bf16x8*)&Hs[(rt * 16 + i) * HS_LD + (ks + 1) * 32 + q * 8];
#pragma unroll
            for (int ct = 0; ct < 2; ct++)
                bn2[ct] =
                    *(const bf16x8*)&W2T[(w * 32 + ct * 16 + i) * HD2 + (ks + 1) * 32 + q * 8];
        }
#pragma unroll
        for (int rt = 0; rt < 2; rt++)
#pragma unroll
            for (int ct = 0; ct < 2; ct++)
                acc2[rt][ct] = __builtin_amdgcn_mfma_f32_16x16x32_bf16(hc[rt], bc[ct],
                                                                      acc2[rt][ct], 0, 0, 0);
        if (ks < 7) {
#pragma unroll
            for (int rt = 0; rt < 2; rt++) hc[rt] = hn[rt];
#pragma unroll
            for (int ct = 0; ct < 2; ct++) bc[ct] = bn2[ct];
        }
    }

    // ---- conv-out (+b2) -> bf16 LDS tile Ht (C-layout scatter; LDS absorbs it) ----
#pragma unroll
    for (int ct = 0; ct < 2; ct++) {
        float bb = b2l[w * 32 + ct * 16 + i];
#pragma unroll
        for (int rt = 0; rt < 2; rt++)
#pragma unroll
            for (int r = 0; r < 4; r++)
                Ht[(rt * 16 + q * 4 + r) * HT_LD + w * 32 + ct * 16 + i] =
                    f2b(acc2[rt][ct][r] + bb);
    }
    __syncthreads();

    // ---- row-wise COALESCED epilogue: residual add, h store, LN(128), zb store ----
    {
        const unsigned int* Ht32 = (const unsigned int*)Ht;
        unsigned int* h32 = (unsigned int*)h;
        unsigned int* zb32 = (unsigned int*)zb;
        float2 gg = *(const float2*)&gn[lane * 2];
        float2 cc = *(const float2*)&bn[lane * 2];
        for (int rr = w; rr < BM; rr += 4) {
            int row = nb + rr;
            if (row >= NN) break;
            unsigned int tv = Ht32[rr * (HT_LD / 2) + lane];
            float cx = b2f((unsigned short)tv), cy = b2f((unsigned short)(tv >> 16));
            if (add_residual) {
                unsigned int hv = h32[(size_t)row * 64 + lane];
                cx += b2f((unsigned short)hv);
                cy += b2f((unsigned short)(hv >> 16));
            }
            h32[(size_t)row * 64 + lane] = pack2(cx, cy);
            float s = cx + cy, sq = cx * cx + cy * cy;
#pragma unroll
            for (int m = 32; m >= 1; m >>= 1) {
                s += __shfl_xor(s, m);
                sq += __shfl_xor(sq, m);
            }
            float mu = s * (1.f / 128.f);
            float var = sq * (1.f / 128.f) - mu * mu;
            float inv = rsqrtf(var + LNEPS);
            float z0 = fmaxf(fmaf((cx - mu) * inv, gg.x, cc.x), 0.f);
            float z1 = fmaxf(fmaf((cy - mu) * inv, gg.y, cc.y), 0.f);
            zb32[(size_t)row * 64 + lane] = pack2(z0, z1);
        }
    }
}

// ---------------- atomic-free global mean pool (batch is sorted) ----------------
__global__ void k_pool(const unsigned short* __restrict__ zb, const int* __restrict__ gstart,
                       float* __restrict__ out) {
    int g = blockIdx.x;
    int c = threadIdx.x;  // 128
    int a = gstart[g], b = gstart[g + 1];
    float s0 = 0.f, s1 = 0.f;
    int n = a;
    for (; n + 2 <= b; n += 2) {
        s0 += b2f(zb[(size_t)n * HD + c]);
        s1 += b2f(zb[(size_t)(n + 1) * HD + c]);
    }
    if (n < b) s0 += b2f(zb[(size_t)n * HD + c]);
    out[g * HD + c] = (s0 + s1) / fmaxf((float)(b - a), 1.f);
}

// ---------------- launch ----------------
extern "C" void kernel_launch(void* const* d_in, const int* in_sizes, int n_in, void* d_out,
                              int out_size, void* d_ws, size_t ws_size, hipStream_t stream) {
    const float* x     = (const float*)d_in[0];
    const int* ei      = (const int*)d_in[1];
    const float* eattr = (const float*)d_in[2];
    const int* batch   = (const int*)d_in[3];
    const float* encW  = (const float*)d_in[4];
    const float* encB  = (const float*)d_in[5];
    const float* eW    = (const float*)d_in[6];
    const float* eB    = (const float*)d_in[7];
    const float* ln_g  = (const float*)d_in[8];
    const float* ln_b  = (const float*)d_in[9];
    const float* W1    = (const float*)d_in[10];
    const float* b1    = (const float*)d_in[11];
    const float* mlg   = (const float*)d_in[12];
    const float* mlb   = (const float*)d_in[13];
    const float* W2    = (const float*)d_in[14];
    const float* b2    = (const float*)d_in[15];
    const float* t     = (const float*)d_in[16];
    const int* src = ei;
    const int* dst = ei + NE;

    char* w = (char*)d_ws;
    auto alloc = [&](size_t bytes) {
        char* p = w;
        w += (bytes + 255) & ~size_t(255);
        return p;
    };
    unsigned short* h    = (unsigned short*)alloc(sizeof(unsigned short) * NN * HD);
    unsigned short* zb   = (unsigned short*)alloc(sizeof(unsigned short) * NN * HD);
    unsigned int* outb   = (unsigned int*)alloc(sizeof(unsigned int) * NN * HD / 2);
    float4* aperm        = (float4*)alloc(sizeof(float4) * NE);
    int* row_start       = (int*)alloc(sizeof(int) * (NN + 1));
    int* counts          = (int*)alloc(sizeof(int) * NN);
    int* cursor          = (int*)alloc(sizeof(int) * NN);
    int* incl            = (int*)alloc(sizeof(int) * NN);
    int* bsum            = (int*)alloc(sizeof(int) * 128);
    int* boff            = (int*)alloc(sizeof(int) * 128);
    int* gstart          = (int*)alloc(sizeof(int) * (NG + 1));
    unsigned short* W1T  = (unsigned short*)alloc(sizeof(unsigned short) * NL * HD * HD2);
    unsigned short* W2T  = (unsigned short*)alloc(sizeof(unsigned short) * NL * HD2 * HD);

    hipMemsetAsync(counts, 0, sizeof(int) * NN, stream);
    hipMemsetAsync(cursor, 0, sizeof(int) * NN, stream);

    k_setup<<<PREP_BLKS + ENC_BLKS + HIST_BLKS, 256, 0, stream>>>(x, encW, encB, zb, W1, W2,
                                                                  W1T, W2T, dst, counts);
    k_scan1<<<NSB, SCAN_B, 0, stream>>>(counts, incl, bsum);
    k_scan2<<<1, 128, 0, stream>>>(bsum, boff, NSB);
    k_scan3g<<<NSB + 2, SCAN_B, 0, stream>>>(incl, boff, row_start, batch, gstart);
    k_scatter<<<(NE + 255) / 256, 256, 0, stream>>>(src, dst, eattr, row_start, cursor, aperm);

    for (int l = 0; l < NL; l++) {
        k_aggregate<<<NN / 2, 256, 0, stream>>>(zb, aperm, row_start, eW, eB, t, l, outb);
        int ln_next = (l + 1) % NL;  // layer 3 fuses the final ln (reuses layer-0 params)
        k_mlp<<<(NN + BM - 1) / BM, 256, 0, stream>>>(
            (const unsigned short*)outb, W1T + (size_t)l * HD * HD2, b1 + l * HD2,
            mlg + l * HD2, mlb + l * HD2, W2T + (size_t)l * HD2 * HD, b2 + l * HD, h,
            ln_g + ln_next * HD, ln_b + ln_next * HD, zb, l > 0);
    }
    k_pool<<<NG, HD, 0, stream>>>(zb, gstart, (float*)d_out);
}

// Round 12
// 509.113 us; speedup vs baseline: 1.2780x; 1.0743x over previous
//
#include <hip/hip_runtime.h>

#define NN 50000
#define NE 500000
#define HD 128
#define HD2 256
#define NL 4
#define NG 1000

constexpr float MSG_EPS = 1e-7f;
constexpr float LNEPS   = 1e-5f;

typedef float  f32x4  __attribute__((ext_vector_type(4)));
typedef float  f32x2  __attribute__((ext_vector_type(2)));
typedef __bf16 bf16x8 __attribute__((ext_vector_type(8)));

__device__ __forceinline__ unsigned short f2b(float f) {
    unsigned int u = __float_as_uint(f);
    unsigned int r = u + 0x7FFFu + ((u >> 16) & 1u);
    return (unsigned short)(r >> 16);
}
__device__ __forceinline__ float b2f(unsigned short h) {
    return __uint_as_float(((unsigned int)h) << 16);
}
__device__ __forceinline__ unsigned int pack2(float a, float b) {
    return (unsigned int)f2b(a) | ((unsigned int)f2b(b) << 16);
}

// ---------------- merged setup: weight prep + node encoder + dst histogram ----------
#define PREP_BLKS 512
#define ENC_BLKS 25000  // 2 nodes per 256-thr block
#define HIST_BLKS ((NE + 255) / 256)

__global__ void k_setup(const float* __restrict__ x, const float* __restrict__ encW,
                        const float* __restrict__ encB, unsigned short* __restrict__ zb,
                        const float* __restrict__ W1, const float* __restrict__ W2,
                        unsigned short* __restrict__ W1T, unsigned short* __restrict__ W2T,
                        const int* __restrict__ dst, int* __restrict__ counts) {
    int bid = blockIdx.x, tid = threadIdx.x;
    if (bid < PREP_BLKS) {
        int idx = bid * 256 + tid;  // 131072 total
        {
            int k = idx & 127, n = (idx >> 7) & 255, l = idx >> 15;
            W1T[idx] = f2b(W1[(l * 128 + k) * 256 + n]);
        }
        {
            int k = idx & 255, n = (idx >> 8) & 127, l = idx >> 15;
            W2T[idx] = f2b(W2[(l * 256 + k) * 128 + n]);
        }
    } else if (bid < PREP_BLKS + ENC_BLKS) {
        int n = (bid - PREP_BLKS) * 2 + (tid >> 7);
        int c = tid & 127;
        float xr[9];
#pragma unroll
        for (int k = 0; k < 9; k++) xr[k] = x[n * 9 + k];
        float acc = encB[c];
#pragma unroll
        for (int k = 0; k < 9; k++) acc = fmaf(xr[k], encW[k * HD + c], acc);
        zb[(size_t)n * HD + c] = f2b(acc);
    } else {
        int e = (bid - PREP_BLKS - ENC_BLKS) * 256 + tid;
        if (e < NE) atomicAdd(&counts[dst[e]], 1);
    }
}

// ---------------- CSR scan ----------------
#define SCAN_B 512
#define NSB ((NN + SCAN_B - 1) / SCAN_B)  // 98

__global__ void k_scan1(const int* __restrict__ counts, int* __restrict__ incl,
                        int* __restrict__ bsum) {
    __shared__ int s[SCAN_B];
    int i = blockIdx.x * SCAN_B + threadIdx.x;
    int v = (i < NN) ? counts[i] : 0;
    s[threadIdx.x] = v;
    __syncthreads();
    for (int off = 1; off < SCAN_B; off <<= 1) {
        int t = (threadIdx.x >= off) ? s[threadIdx.x - off] : 0;
        __syncthreads();
        s[threadIdx.x] += t;
        __syncthreads();
    }
    if (i < NN) incl[i] = s[threadIdx.x];
    if (threadIdx.x == SCAN_B - 1) bsum[blockIdx.x] = s[threadIdx.x];
}

__global__ void k_scan2(const int* __restrict__ bsum, int* __restrict__ boff, int nb) {
    __shared__ int s[128];
    int v = (threadIdx.x < nb) ? bsum[threadIdx.x] : 0;
    s[threadIdx.x] = v;
    __syncthreads();
    for (int off = 1; off < 128; off <<= 1) {
        int t = (threadIdx.x >= off) ? s[threadIdx.x - off] : 0;
        __syncthreads();
        s[threadIdx.x] += t;
        __syncthreads();
    }
    if (threadIdx.x < nb) boff[threadIdx.x] = s[threadIdx.x] - v;  // exclusive
}

// scan finalize + group-bounds binary search (merged)
__global__ void k_scan3g(const int* __restrict__ incl, const int* __restrict__ boff,
                         int* __restrict__ row_start, const int* __restrict__ batch,
                         int* __restrict__ gstart) {
    if (blockIdx.x < NSB) {
        int i = blockIdx.x * SCAN_B + threadIdx.x;
        if (i < NN) row_start[i + 1] = incl[i] + boff[blockIdx.x];
        if (i == 0) row_start[0] = 0;
    } else {
        int g = (blockIdx.x - NSB) * SCAN_B + threadIdx.x;
        if (g > NG) return;
        int lo = 0, hi = NN;
        while (lo < hi) {
            int mid = (lo + hi) >> 1;
            if (batch[mid] < g) lo = mid + 1;
            else hi = mid;
        }
        gstart[g] = lo;
    }
}

// pack {attr0, attr1, attr2, src} per CSR slot
__global__ void k_scatter(const int* __restrict__ src, const int* __restrict__ dst,
                          const float* __restrict__ eattr, const int* __restrict__ row_start,
                          int* __restrict__ cursor, float4* __restrict__ aperm) {
    int e = blockIdx.x * blockDim.x + threadIdx.x;
    if (e >= NE) return;
    int d = dst[e];
    int p = row_start[d] + atomicAdd(&cursor[d], 1);
    float4 v;
    v.x = eattr[e * 3 + 0];
    v.y = eattr[e * 3 + 1];
    v.z = eattr[e * 3 + 2];
    v.w = __int_as_float(src[e]);
    aperm[p] = v;
}

// ---------------- per-edge softmax-agg accumulate (2 ch/lane, packed fp32) ----------
// eps folded out of the loop: exp(t*(m+eps)) scales num & wm identically (cancels in
// the ratio); sum((m+eps)*alpha) = sum(m*alpha) + eps  ->  added once in epilogue.
__device__ __forceinline__ void edge_acc2(float4 a, unsigned int zz, f32x2 w0, f32x2 w1,
                                          f32x2 w2, f32x2 bb, float tv, f32x2& num,
                                          f32x2& wm) {
    f32x2 z;
    z.x = b2f((unsigned short)zz);
    z.y = b2f((unsigned short)(zz >> 16));
    f32x2 m = z + bb + a.x * w0 + a.y * w1 + a.z * w2;  // v_pk_fma chain
    m.x = fmaxf(m.x, 0.f);
    m.y = fmaxf(m.y, 0.f);
    f32x2 tm = tv * m;  // v_pk_mul
    f32x2 e;
    e.x = __expf(tm.x);
    e.y = __expf(tm.y);
    num += e;       // v_pk_add
    wm += m * e;    // v_pk_fma
}

// ---------------- softmax aggregation: one wave per node, 2 ch/lane, unroll-8 ------
// Gather base scalarized via readfirstlane (sj is wave-uniform -> SALU addr + saddr load).
__global__ __launch_bounds__(256) void k_aggregate(const unsigned short* __restrict__ zbin,
                                                   const float4* __restrict__ aperm,
                                                   const int* __restrict__ row_start,
                                                   const float* __restrict__ We,
                                                   const float* __restrict__ be,
                                                   const float* __restrict__ t, int layer,
                                                   unsigned int* __restrict__ outb) {
    int w = threadIdx.x >> 6, lane = threadIdx.x & 63;
    int n = blockIdx.x * 4 + w;
    if (n >= NN) return;
    int c = lane * 2;
    f32x2 w0 = *(const f32x2*)&We[c];
    f32x2 w1 = *(const f32x2*)&We[HD + c];
    f32x2 w2 = *(const f32x2*)&We[2 * HD + c];
    f32x2 bb = *(const f32x2*)&be[c];
    float tv = t[layer];
    int s0 = row_start[n], s1 = row_start[n + 1];
    f32x2 num = (f32x2){0.f, 0.f}, wm = (f32x2){0.f, 0.f};
    const unsigned int* z32 = (const unsigned int*)zbin;
    int p = s0;
    for (; p + 8 <= s1; p += 8) {
        float4 A[8];
#pragma unroll
        for (int j = 0; j < 8; j++) A[j] = aperm[p + j];
        unsigned int Z[8];
#pragma unroll
        for (int j = 0; j < 8; j++) {
            int sj = __builtin_amdgcn_readfirstlane(__float_as_int(A[j].w));
            Z[j] = z32[(size_t)sj * 64 + lane];
        }
#pragma unroll
        for (int j = 0; j < 8; j++) edge_acc2(A[j], Z[j], w0, w1, w2, bb, tv, num, wm);
    }
    for (; p + 4 <= s1; p += 4) {
        float4 A[4];
#pragma unroll
        for (int j = 0; j < 4; j++) A[j] = aperm[p + j];
        unsigned int Z[4];
#pragma unroll
        for (int j = 0; j < 4; j++) {
            int sj = __builtin_amdgcn_readfirstlane(__float_as_int(A[j].w));
            Z[j] = z32[(size_t)sj * 64 + lane];
        }
#pragma unroll
        for (int j = 0; j < 4; j++) edge_acc2(A[j], Z[j], w0, w1, w2, bb, tv, num, wm);
    }
    for (; p < s1; p++) {
        float4 a = aperm[p];
        int sj = __builtin_amdgcn_readfirstlane(__float_as_int(a.w));
        unsigned int zz = z32[(size_t)sj * 64 + lane];
        edge_acc2(a, zz, w0, w1, w2, bb, tv, num, wm);
    }
    unsigned int zn = z32[(size_t)n * 64 + lane];
    bool has = s1 > s0;
    float ox = (has ? (wm.x / num.x + MSG_EPS) : 0.f) + b2f((unsigned short)zn);
    float oy = (has ? (wm.y / num.y + MSG_EPS) : 0.f) + b2f((unsigned short)(zn >> 16));
    outb[(size_t)n * 64 + lane] = pack2(ox, oy);
}

// ---------------- fused MFMA MLP + next-layer LN+relu (R9 version) ----------------
// hnew = (add? h : 0) + relu(LN(A@W1+b1))@W2+b2 ; h=bf16(hnew); zb=bf16(relu(LN_next(hnew)))
// BM=32, 4 waves. In-register LN1 stats (st1 LDS exchange). Register lookahead GEMMs.
// GEMM2 out -> bf16 LDS tile Ht (C-layout scatter), then row-wise COALESCED epilogue.
#define BM 32
#define HS_LD 264  // bf16 row stride (256+8)
#define HT_LD 136  // bf16 row stride (128+8); as uint: 68

__global__ __launch_bounds__(256) void k_mlp(const unsigned short* __restrict__ outb,
                                             const unsigned short* __restrict__ W1T,
                                             const float* __restrict__ b1l,
                                             const float* __restrict__ lgl,
                                             const float* __restrict__ lbl,
                                             const unsigned short* __restrict__ W2T,
                                             const float* __restrict__ b2l,
                                             unsigned short* __restrict__ h,
                                             const float* __restrict__ gn,
                                             const float* __restrict__ bn,
                                             unsigned short* __restrict__ zb,
                                             int add_residual) {
    __shared__ __align__(16) unsigned short Hs[BM * HS_LD];  // 16896 B
    __shared__ __align__(16) unsigned short Ht[BM * HT_LD];  // 8704 B
    __shared__ __align__(16) float2 st1[2][16][4];           // 1024 B

    int nb = blockIdx.x * BM;
    int tid = threadIdx.x;
    int w = tid >> 6, lane = tid & 63, q = lane >> 4, i = lane & 15;

    // ---- GEMM1: 32x256, K=128; A from global bf16 outb, 1-step lookahead ----
    f32x4 acc[2][4];
#pragma unroll
    for (int rt = 0; rt < 2; rt++)
#pragma unroll
        for (int ct = 0; ct < 4; ct++) acc[rt][ct] = (f32x4){0.f, 0.f, 0.f, 0.f};

    bf16x8 acur[2], bcur[4];
#pragma unroll
    for (int rt = 0; rt < 2; rt++) {
        int row = nb + rt * 16 + i;
        acur[rt] = (row < NN) ? *(const bf16x8*)&outb[(size_t)row * HD + q * 8]
                              : (bf16x8)(__bf16)0.f;
    }
#pragma unroll
    for (int ct = 0; ct < 4; ct++)
        bcur[ct] = *(const bf16x8*)&W1T[(w * 64 + ct * 16 + i) * HD + q * 8];

#pragma unroll
    for (int ks = 0; ks < 4; ks++) {
        bf16x8 anxt[2], bnxt[4];
        if (ks < 3) {
#pragma unroll
            for (int rt = 0; rt < 2; rt++) {
                int row = nb + rt * 16 + i;
                anxt[rt] = (row < NN)
                               ? *(const bf16x8*)&outb[(size_t)row * HD + (ks + 1) * 32 + q * 8]
                               : (bf16x8)(__bf16)0.f;
            }
#pragma unroll
            for (int ct = 0; ct < 4; ct++)
                bnxt[ct] =
                    *(const bf16x8*)&W1T[(w * 64 + ct * 16 + i) * HD + (ks + 1) * 32 + q * 8];
        }
#pragma unroll
        for (int rt = 0; rt < 2; rt++)
#pragma unroll
            for (int ct = 0; ct < 4; ct++)
                acc[rt][ct] =
                    __builtin_amdgcn_mfma_f32_16x16x32_bf16(acur[rt], bcur[ct], acc[rt][ct],
                                                            0, 0, 0);
        if (ks < 3) {
#pragma unroll
            for (int rt = 0; rt < 2; rt++) acur[rt] = anxt[rt];
#pragma unroll
            for (int ct = 0; ct < 4; ct++) bcur[ct] = bnxt[ct];
        }
    }

    // ---- +b1 ----
#pragma unroll
    for (int ct = 0; ct < 4; ct++) {
        float bb = b1l[w * 64 + ct * 16 + i];
#pragma unroll
        for (int rt = 0; rt < 2; rt++)
#pragma unroll
            for (int r = 0; r < 4; r++) acc[rt][ct][r] += bb;
    }

    // ---- LN(256) stats in-register + cross-wave exchange ----
    {
        float sv[2][4], qv[2][4];
#pragma unroll
        for (int rt = 0; rt < 2; rt++)
#pragma unroll
            for (int r = 0; r < 4; r++) {
                float s = acc[rt][0][r] + acc[rt][1][r] + acc[rt][2][r] + acc[rt][3][r];
                float sq = 0.f;
#pragma unroll
                for (int ct = 0; ct < 4; ct++) sq = fmaf(acc[rt][ct][r], acc[rt][ct][r], sq);
                sv[rt][r] = s;
                qv[rt][r] = sq;
            }
#pragma unroll
        for (int m = 1; m <= 8; m <<= 1)
#pragma unroll
            for (int rt = 0; rt < 2; rt++)
#pragma unroll
                for (int r = 0; r < 4; r++) {
                    sv[rt][r] += __shfl_xor(sv[rt][r], m);
                    qv[rt][r] += __shfl_xor(qv[rt][r], m);
                }
        if (i == 0) {
#pragma unroll
            for (int rt = 0; rt < 2; rt++)
#pragma unroll
                for (int r = 0; r < 4; r++)
                    st1[rt][q * 4 + r][w] = make_float2(sv[rt][r], qv[rt][r]);
        }
    }
    __syncthreads();

    {
        float mu[2][4], inv[2][4];
#pragma unroll
        for (int rt = 0; rt < 2; rt++)
#pragma unroll
            for (int r = 0; r < 4; r++) {
                const float4* sp = (const float4*)&st1[rt][q * 4 + r][0];
                float4 a = sp[0], b = sp[1];
                float S = a.x + a.z + b.x + b.z;
                float Q = a.y + a.w + b.y + b.w;
                float m_ = S * (1.f / 256.f);
                float v_ = Q * (1.f / 256.f) - m_ * m_;
                mu[rt][r] = m_;
                inv[rt][r] = rsqrtf(v_ + LNEPS);
            }
#pragma unroll
        for (int ct = 0; ct < 4; ct++) {
            float g = lgl[w * 64 + ct * 16 + i];
            float c = lbl[w * 64 + ct * 16 + i];
#pragma unroll
            for (int rt = 0; rt < 2; rt++)
#pragma unroll
                for (int r = 0; r < 4; r++) {
                    float v =
                        fmaxf(fmaf((acc[rt][ct][r] - mu[rt][r]) * inv[rt][r], g, c), 0.f);
                    Hs[(rt * 16 + q * 4 + r) * HS_LD + w * 64 + ct * 16 + i] = f2b(v);
                }
        }
    }
    __syncthreads();

    // ---- GEMM2: 32x128, K=256; A from Hs, 1-step lookahead ----
    f32x4 acc2[2][2];
#pragma unroll
    for (int rt = 0; rt < 2; rt++)
#pragma unroll
        for (int ct = 0; ct < 2; ct++) acc2[rt][ct] = (f32x4){0.f, 0.f, 0.f, 0.f};

    bf16x8 hc[2], bc[2];
#pragma unroll
    for (int rt = 0; rt < 2; rt++) hc[rt] = *(const bf16x8*)&Hs[(rt * 16 + i) * HS_LD + q * 8];
#pragma unroll
    for (int ct = 0; ct < 2; ct++)
        bc[ct] = *(const bf16x8*)&W2T[(w * 32 + ct * 16 + i) * HD2 + q * 8];

#pragma unroll
    for (int ks = 0; ks < 8; ks++) {
        bf16x8 hn[2], bn2[2];
        if (ks < 7) {
#pragma unroll
            for (int rt = 0; rt < 2; rt++)
                hn[rt] = *(const bf16x8*)&Hs[(rt * 16 + i) * HS_LD + (ks + 1) * 32 + q * 8];
#pragma unroll
            for (int ct = 0; ct < 2; ct++)
                bn2[ct] =
                    *(const bf16x8*)&W2T[(w * 32 + ct * 16 + i) * HD2 + (ks + 1) * 32 + q * 8];
        }
#pragma unroll
        for (int rt = 0; rt < 2; rt++)
#pragma unroll
            for (int ct = 0; ct < 2; ct++)
                acc2[rt][ct] = __builtin_amdgcn_mfma_f32_16x16x32_bf16(hc[rt], bc[ct],
                                                                      acc2[rt][ct], 0, 0, 0);
        if (ks < 7) {
#pragma unroll
            for (int rt = 0; rt < 2; rt++) hc[rt] = hn[rt];
#pragma unroll
            for (int ct = 0; ct < 2; ct++) bc[ct] = bn2[ct];
        }
    }

    // ---- conv-out (+b2) -> bf16 LDS tile Ht (C-layout scatter; LDS absorbs it) ----
#pragma unroll
    for (int ct = 0; ct < 2; ct++) {
        float bb = b2l[w * 32 + ct * 16 + i];
#pragma unroll
        for (int rt = 0; rt < 2; rt++)
#pragma unroll
            for (int r = 0; r < 4; r++)
                Ht[(rt * 16 + q * 4 + r) * HT_LD + w * 32 + ct * 16 + i] =
                    f2b(acc2[rt][ct][r] + bb);
    }
    __syncthreads();

    // ---- row-wise COALESCED epilogue: residual add, h store, LN(128), zb store ----
    {
        const unsigned int* Ht32 = (const unsigned int*)Ht;
        unsigned int* h32 = (unsigned int*)h;
        unsigned int* zb32 = (unsigned int*)zb;
        float2 gg = *(const float2*)&gn[lane * 2];
        float2 cc = *(const float2*)&bn[lane * 2];
        for (int rr = w; rr < BM; rr += 4) {
            int row = nb + rr;
            if (row >= NN) break;
            unsigned int tv = Ht32[rr * (HT_LD / 2) + lane];
            float cx = b2f((unsigned short)tv), cy = b2f((unsigned short)(tv >> 16));
            if (add_residual) {
                unsigned int hv = h32[(size_t)row * 64 + lane];
                cx += b2f((unsigned short)hv);
                cy += b2f((unsigned short)(hv >> 16));
            }
            h32[(size_t)row * 64 + lane] = pack2(cx, cy);
            float s = cx + cy, sq = cx * cx + cy * cy;
#pragma unroll
            for (int m = 32; m >= 1; m >>= 1) {
                s += __shfl_xor(s, m);
                sq += __shfl_xor(sq, m);
            }
            float mu = s * (1.f / 128.f);
            float var = sq * (1.f / 128.f) - mu * mu;
            float inv = rsqrtf(var + LNEPS);
            float z0 = fmaxf(fmaf((cx - mu) * inv, gg.x, cc.x), 0.f);
            float z1 = fmaxf(fmaf((cy - mu) * inv, gg.y, cc.y), 0.f);
            zb32[(size_t)row * 64 + lane] = pack2(z0, z1);
        }
    }
}

// ---------------- atomic-free global mean pool (batch is sorted) ----------------
__global__ void k_pool(const unsigned short* __restrict__ zb, const int* __restrict__ gstart,
                       float* __restrict__ out) {
    int g = blockIdx.x;
    int c = threadIdx.x;  // 128
    int a = gstart[g], b = gstart[g + 1];
    float s0 = 0.f, s1 = 0.f;
    int n = a;
    for (; n + 2 <= b; n += 2) {
        s0 += b2f(zb[(size_t)n * HD + c]);
        s1 += b2f(zb[(size_t)(n + 1) * HD + c]);
    }
    if (n < b) s0 += b2f(zb[(size_t)n * HD + c]);
    out[g * HD + c] = (s0 + s1) / fmaxf((float)(b - a), 1.f);
}

// ---------------- launch ----------------
extern "C" void kernel_launch(void* const* d_in, const int* in_sizes, int n_in, void* d_out,
                              int out_size, void* d_ws, size_t ws_size, hipStream_t stream) {
    const float* x     = (const float*)d_in[0];
    const int* ei      = (const int*)d_in[1];
    const float* eattr = (const float*)d_in[2];
    const int* batch   = (const int*)d_in[3];
    const float* encW  = (const float*)d_in[4];
    const float* encB  = (const float*)d_in[5];
    const float* eW    = (const float*)d_in[6];
    const float* eB    = (const float*)d_in[7];
    const float* ln_g  = (const float*)d_in[8];
    const float* ln_b  = (const float*)d_in[9];
    const float* W1    = (const float*)d_in[10];
    const float* b1    = (const float*)d_in[11];
    const float* mlg   = (const float*)d_in[12];
    const float* mlb   = (const float*)d_in[13];
    const float* W2    = (const float*)d_in[14];
    const float* b2    = (const float*)d_in[15];
    const float* t     = (const float*)d_in[16];
    const int* src = ei;
    const int* dst = ei + NE;

    char* w = (char*)d_ws;
    auto alloc = [&](size_t bytes) {
        char* p = w;
        w += (bytes + 255) & ~size_t(255);
        return p;
    };
    unsigned short* h    = (unsigned short*)alloc(sizeof(unsigned short) * NN * HD);
    unsigned short* zb   = (unsigned short*)alloc(sizeof(unsigned short) * NN * HD);
    unsigned int* outb   = (unsigned int*)alloc(sizeof(unsigned int) * NN * HD / 2);
    float4* aperm        = (float4*)alloc(sizeof(float4) * NE);
    int* row_start       = (int*)alloc(sizeof(int) * (NN + 1));
    int* counts          = (int*)alloc(sizeof(int) * NN);
    int* cursor          = (int*)alloc(sizeof(int) * NN);
    int* incl            = (int*)alloc(sizeof(int) * NN);
    int* bsum            = (int*)alloc(sizeof(int) * 128);
    int* boff            = (int*)alloc(sizeof(int) * 128);
    int* gstart          = (int*)alloc(sizeof(int) * (NG + 1));
    unsigned short* W1T  = (unsigned short*)alloc(sizeof(unsigned short) * NL * HD * HD2);
    unsigned short* W2T  = (unsigned short*)alloc(sizeof(unsigned short) * NL * HD2 * HD);

    hipMemsetAsync(counts, 0, sizeof(int) * NN, stream);
    hipMemsetAsync(cursor, 0, sizeof(int) * NN, stream);

    k_setup<<<PREP_BLKS + ENC_BLKS + HIST_BLKS, 256, 0, stream>>>(x, encW, encB, zb, W1, W2,
                                                                  W1T, W2T, dst, counts);
    k_scan1<<<NSB, SCAN_B, 0, stream>>>(counts, incl, bsum);
    k_scan2<<<1, 128, 0, stream>>>(bsum, boff, NSB);
    k_scan3g<<<NSB + 2, SCAN_B, 0, stream>>>(incl, boff, row_start, batch, gstart);
    k_scatter<<<(NE + 255) / 256, 256, 0, stream>>>(src, dst, eattr, row_start, cursor, aperm);

    for (int l = 0; l < NL; l++) {
        k_aggregate<<<(NN + 3) / 4, 256, 0, stream>>>(zb, aperm, row_start, eW, eB, t, l, outb);
        int ln_next = (l + 1) % NL;  // layer 3 fuses the final ln (reuses layer-0 params)
        k_mlp<<<(NN + BM - 1) / BM, 256, 0, stream>>>(
            (const unsigned short*)outb, W1T + (size_t)l * HD * HD2, b1 + l * HD2,
            mlg + l * HD2, mlb + l * HD2, W2T + (size_t)l * HD2 * HD, b2 + l * HD, h,
            ln_g + ln_next * HD, ln_b + ln_next * HD, zb, l > 0);
    }
    k_pool<<<NG, HD, 0, stream>>>(zb, gstart, (float*)d_out);
}